// Round 4
// baseline (380.011 us; speedup 1.0000x reference)
//
#include <hip/hip_runtime.h>

// Problem constants
static constexpr int   Cc  = 21;
static constexpr int   HWn = 512 * 512;         // 262144 = 2^18
static constexpr int   Nn  = 8 * HWn;           // 2097152 pixels
static constexpr float MAXM  = 0.5f;
static constexpr float Sc    = 30.0f;
static constexpr float LOG2E = 1.4426950408889634f;
static constexpr float LN2   = 0.6931471805599453f;

static constexpr int HIST_BLOCKS = 512;               // 512 blk * 256 thr * 4 int4 = Nn/4
static constexpr int LOSS_BLOCKS = Nn / 4 / 256;      // 2048

// ws layout (bytes): 0: int counts[21] ; 96: uint done-flag ; 128: double partial[2048]
static constexpr int WS_COUNTS = 0;
static constexpr int WS_FLAG   = 96;
static constexpr int WS_PART   = 128;

// ---------------------------------------------------------------------------
// K1: class histogram. 512 blocks (4 int4 per thread). Per-WAVE LDS
// sub-histograms cut same-address LDS atomic serialization 4x; then 21
// global atomics per block (512-deep per address — negligible tail).
__global__ __launch_bounds__(256) void hist_kernel(const int4* __restrict__ t4,
                                                   int* __restrict__ counts) {
    __shared__ int lh[4][Cc];
    int t = threadIdx.x;
    if (t < 4 * Cc) ((int*)lh)[t] = 0;
    __syncthreads();
    int wave = t >> 6;
    int base = blockIdx.x * (256 * 4) + t;
    #pragma unroll
    for (int i = 0; i < 4; ++i) {
        int4 v = t4[base + i * 256];
        atomicAdd(&lh[wave][v.x], 1);
        atomicAdd(&lh[wave][v.y], 1);
        atomicAdd(&lh[wave][v.z], 1);
        atomicAdd(&lh[wave][v.w], 1);
    }
    __syncthreads();
    if (t < Cc)
        atomicAdd(&counts[t], lh[0][t] + lh[1][t] + lh[2][t] + lh[3][t]);
}

// ---------------------------------------------------------------------------
// K2: main loss — the round-0 proven body (float4 x[21] tile, 4 pixels per
// thread, two passes over registers), with the tile PINNED via empty inline
// asm. Rounds 1-3 proved the compiler remats __restrict loads instead of
// keeping the tile live (VGPR 60/24/36 -> 157-190us, latency-bound). The
// "+v" asm outputs are opaque: they CANNOT be rematerialized from memory,
// so all 84 components stay in VGPRs from load to pass 2 (MLP=21 x 16B).
// m_list is fused per-wave via shuffles (no LDS, no barrier in the hot
// path — round 1's barrier variant is what broke the tile). Per-block
// result is a plain store; final mean via fenced last-block-done.
__global__ __launch_bounds__(256, 2) void loss_kernel(const float* __restrict__ pred,
                                                      const int4* __restrict__ t4,
                                                      const int* __restrict__ counts,
                                                      double* __restrict__ partial,
                                                      unsigned int* __restrict__ flag,
                                                      float* __restrict__ out) {
    __shared__ double wsum[4];
    __shared__ bool   s_last;
    int t    = threadIdx.x;
    int lane = t & 63;

    int tid = blockIdx.x * 256 + t;           // tid in [0, Nn/4)
    int n0  = tid * 4;
    int b   = n0 >> 18;                       // HWn = 2^18
    int hw  = n0 & (HWn - 1);
    const float4* p4 = (const float4*)(pred + (size_t)b * Cc * HWn + hw);

    // issue all 21 coalesced float4 loads back-to-back (MLP=21)
    float4 x[Cc];
    #pragma unroll
    for (int c = 0; c < Cc; ++c) x[c] = p4[(size_t)c * (HWn / 4)];

    // PIN the tile: outputs are opaque to the optimizer -> no remat, no
    // reload; 84 components are forced live in VGPRs until last use.
    #pragma unroll
    for (int c = 0; c < Cc; ++c)
        asm volatile("" : "+v"(x[c].x), "+v"(x[c].y), "+v"(x[c].z), "+v"(x[c].w));

    int4 y4 = t4[tid];

    // per-wave m_list via shuffles (no LDS, no barrier):
    // smv = S*log2e * m_list[c] held in lane c (c < 21)
    float mval = 0.0f;
    if (lane < Cc) {
        float cnt = (float)counts[lane] + 1e-4f;
        mval = 1.0f / sqrtf(sqrtf(cnt));      // x^-0.25, same expr as reference
    }
    float mxm = mval;
    #pragma unroll
    for (int o = 32; o >= 1; o >>= 1) mxm = fmaxf(mxm, __shfl_down(mxm, o));
    mxm = __shfl(mxm, 0);
    float smv = Sc * LOG2E * mval * (MAXM / mxm);

    int ys[4] = {y4.x, y4.y, y4.z, y4.w};
    float smy[4];
    #pragma unroll
    for (int k = 0; k < 4; ++k) smy[k] = __shfl(smv, ys[k]);

    const float S2 = Sc * LOG2E;

    // pass 1: max + target value (base-2 logits), nothing stored
    float mx[4] = {-1e30f, -1e30f, -1e30f, -1e30f};
    float vy[4] = {0.f, 0.f, 0.f, 0.f};
    #pragma unroll
    for (int c = 0; c < Cc; ++c) {
        float xs[4] = {x[c].x, x[c].y, x[c].z, x[c].w};
        #pragma unroll
        for (int k = 0; k < 4; ++k) {
            bool  isy = (c == ys[k]);
            float val = fmaf(S2, xs[k], isy ? -smy[k] : 0.0f);
            mx[k] = fmaxf(mx[k], val);
            vy[k] = isy ? val : vy[k];
        }
    }

    // pass 2: sum of exp2 recomputed from the pinned registers
    float nll2 = 0.0f;
    #pragma unroll
    for (int k = 0; k < 4; ++k) {
        float cb = -mx[k];                    // non-target: val - mx
        float cy = -smy[k] - mx[k];           // target: val - mx
        float sum = 0.0f;
        #pragma unroll
        for (int c = 0; c < Cc; ++c) {
            float xs = (k == 0) ? x[c].x : (k == 1) ? x[c].y : (k == 2) ? x[c].z : x[c].w;
            sum += exp2f(fmaf(S2, xs, (c == ys[k]) ? cy : cb));
        }
        nll2 += __log2f(sum) + mx[k] - vy[k];
    }
    float nll = nll2 * LN2;

    // wave (64-lane) reduce
    #pragma unroll
    for (int o = 32; o >= 1; o >>= 1) nll += __shfl_down(nll, o);

    int wave = t >> 6;
    if ((t & 63) == 0) wsum[wave] = (double)nll;
    __syncthreads();
    if (t == 0) {
        double bsum = wsum[0] + wsum[1] + wsum[2] + wsum[3];
        partial[blockIdx.x] = bsum;           // plain store, no contention
        __threadfence();                      // release partial before flag bump
        unsigned done = atomicAdd(flag, 1u);
        s_last = (done == (unsigned)(LOSS_BLOCKS - 1));
    }
    __syncthreads();

    if (s_last) {
        __threadfence();                      // acquire other blocks' partials
        double sm = 0.0;
        for (int i = t; i < LOSS_BLOCKS; i += 256) sm += partial[i];
        #pragma unroll
        for (int o = 32; o >= 1; o >>= 1) sm += __shfl_down(sm, o);
        if ((t & 63) == 0) wsum[t >> 6] = sm;
        __syncthreads();
        if (t == 0)
            out[0] = (float)((wsum[0] + wsum[1] + wsum[2] + wsum[3]) / (double)Nn);
    }
}

extern "C" void kernel_launch(void* const* d_in, const int* in_sizes, int n_in,
                              void* d_out, int out_size, void* d_ws, size_t ws_size,
                              hipStream_t stream) {
    const float* pred   = (const float*)d_in[0];
    const int*   target = (const int*)d_in[1];
    float*       out    = (float*)d_out;

    char* ws = (char*)d_ws;
    int*          counts  = (int*)(ws + WS_COUNTS);
    unsigned int* flag    = (unsigned int*)(ws + WS_FLAG);
    double*       partial = (double*)(ws + WS_PART);

    hipMemsetAsync(d_ws, 0, 128, stream);     // zero counts + done-flag

    hist_kernel <<<HIST_BLOCKS, 256, 0, stream>>>((const int4*)target, counts);
    loss_kernel <<<LOSS_BLOCKS, 256, 0, stream>>>(pred, (const int4*)target,
                                                  counts, partial, flag, out);
}